// Round 10
// baseline (179.358 us; speedup 1.0000x reference)
//
#include <hip/hip_runtime.h>
#include <hip/hip_bf16.h>

#define EMBED 768
#define NHEADS 12
#define HDIM 64
#define WIN 64
#define BATCH 2
#define SEQ 2048
#define MROWS (BATCH*SEQ)      // 4096
#define NBH (BATCH*NHEADS)     // 24
#define QT 32                  // q rows per attn block
#define KP 160                 // key panel width
#define KPAD 168               // padded LDS cols (bf16 arrays)
#define SPAD 164               // f32 score row stride
#define NWAVES_QKV 2304        // (6*32*3) blocks * 4 waves
#define FILL_PER_WAVE 128      // 49152 rows * 6 slots / 2304 waves

typedef __attribute__((ext_vector_type(8))) short short8;
typedef __attribute__((ext_vector_type(4))) float f32x4;

__device__ __forceinline__ float bf2f(unsigned short u) {
    union { unsigned int i; float f; } z;
    z.i = ((unsigned int)u) << 16;
    return z.f;
}
__device__ __forceinline__ unsigned short f2bf(float f) {
    __hip_bfloat16 h = __float2bfloat16(f);
    return *reinterpret_cast<unsigned short*>(&h);
}

// async global->LDS, 16 B per lane; LDS dest must be waveBase + lane*16
__device__ __forceinline__ void gload16(const unsigned short* g, unsigned short* l) {
    __builtin_amdgcn_global_load_lds(
        (const __attribute__((address_space(1))) unsigned int*)g,
        (__attribute__((address_space(3))) unsigned int*)l,
        16, 0, 0);
}

// ---------------- fused fp32 -> bf16 conversion (7 segments, 1 launch) ----------------
struct CvtArgs {
    const float* src[7];
    unsigned short* dst[7];
    int n4[7];
    int bstart[8];
};

__global__ __launch_bounds__(256) void cvt_all(CvtArgs ca) {
    int bid = blockIdx.x;
    int seg = 0;
#pragma unroll
    for (int s = 0; s < 6; ++s)
        if (bid >= ca.bstart[s + 1]) seg = s + 1;
    int i = (bid - ca.bstart[seg]) * 256 + threadIdx.x;
    if (i < ca.n4[seg]) {
        float4 v = reinterpret_cast<const float4*>(ca.src[seg])[i];
        ushort4 o;
        o.x = f2bf(v.x); o.y = f2bf(v.y); o.z = f2bf(v.z); o.w = f2bf(v.w);
        reinterpret_cast<ushort4*>(ca.dst[seg])[i] = o;
    }
}

// ---------------- bf16 NT GEMM: C[M,N] = A[M,K] * B[N,K]^T + bias ----------------
// FILLER=1 (QKV): also streams far-from-band attn filler segments (1e-6) as NT stores.
struct GArgs {
    const unsigned short* A[3];
    const unsigned short* Bm[3];
    const float* bias[3];
    void* C[3];
    float* fill_out;
};

template<int F32OUT, int FILLER>
__global__ __launch_bounds__(256) void gemm_nt(GArgs ga, int M, int N, int K) {
    const int z = blockIdx.z;
    const unsigned short* __restrict__ A  = ga.A[z];
    const unsigned short* __restrict__ Bm = ga.Bm[z];
    const float* __restrict__ bias = ga.bias[z];

    const int bm = blockIdx.y * 128;
    const int bn = blockIdx.x * 128;

    __shared__ unsigned short As[128 * 32];   // linear [128][32]
    __shared__ unsigned short Bs[128 * 32];

    const int tid = threadIdx.x;
    const int lane = tid & 63;
    const int wid = tid >> 6;
    const int wm = wid >> 1, wn = wid & 1;

    const int gwave = (((blockIdx.z * gridDim.y) + blockIdx.y) * gridDim.x + blockIdx.x) * 4 + wid;

    f32x4 acc[4][4] = {};

    const int fr = lane & 15;
    const int krow = (lane >> 4) * 8;

    for (int k0 = 0; k0 < K; k0 += 32) {
#pragma unroll
        for (int it = 0; it < 2; ++it) {
            int idx = it * 256 + tid;
            int r = idx >> 2;
            int c = (idx & 3) * 8;
            gload16(A + (size_t)(bm + r) * K + k0 + c, &As[idx * 8]);
            gload16(Bm + (size_t)(bn + r) * K + k0 + c, &Bs[idx * 8]);
        }
        __syncthreads();

        // ---- attn filler stores: 6 per lane per k-iter, fire & forget.
        // Items enumerate (row, slot) pairs; slot maps to a segment with
        // |seg - (qi>>8)| >= 2 (provably outside the band +/-64).
        if (FILLER) {
            const f32x4 fillv = {1e-6f, 1e-6f, 1e-6f, 1e-6f};
            int t = k0 >> 5;
#pragma unroll
            for (int s = 0; s < 6; ++s) {
                int item_idx = t * 6 + s;
                if (item_idx < FILL_PER_WAVE) {
                    int item = gwave + item_idx * NWAVES_QKV;  // < 49152*6
                    int row = item / 6;
                    int slot = item - row * 6;
                    int qi = row & (SEQ - 1);
                    int c = qi >> 8;
                    int nN = (c == 0 || c == 7) ? 2 : 3;
                    int thr = (c - 1 > 0) ? c - 1 : 0;
                    int seg = slot + ((slot >= thr) ? nN : 0);
                    if (seg < 8)
                        __builtin_nontemporal_store(fillv,
                            reinterpret_cast<f32x4*>(
                                ga.fill_out + (size_t)row * SEQ + seg * 256 + lane * 4));
                }
            }
        }

        short8 af[4], bfv[4];
#pragma unroll
        for (int mf = 0; mf < 4; ++mf)
            af[mf] = *reinterpret_cast<const short8*>(&As[(wm * 64 + mf * 16 + fr) * 32 + krow]);
#pragma unroll
        for (int nf = 0; nf < 4; ++nf)
            bfv[nf] = *reinterpret_cast<const short8*>(&Bs[(wn * 64 + nf * 16 + fr) * 32 + krow]);
#pragma unroll
        for (int mf = 0; mf < 4; ++mf)
#pragma unroll
            for (int nf = 0; nf < 4; ++nf)
                acc[mf][nf] = __builtin_amdgcn_mfma_f32_16x16x32_bf16(
                    af[mf], bfv[nf], acc[mf][nf], 0, 0, 0);
        __syncthreads();
    }

    const int fq = lane >> 4;
#pragma unroll
    for (int mf = 0; mf < 4; ++mf)
#pragma unroll
        for (int nf = 0; nf < 4; ++nf) {
            int col = bn + wn * 64 + nf * 16 + fr;
            float bv = bias[col];
#pragma unroll
            for (int r = 0; r < 4; ++r) {
                int row = bm + wm * 64 + mf * 16 + fq * 4 + r;
                float v = acc[mf][nf][r] + bv;
                if (F32OUT)
                    reinterpret_cast<float*>(ga.C[z])[(size_t)row * N + col] = v;
                else
                    reinterpret_cast<unsigned short*>(ga.C[z])[(size_t)row * N + col] = f2bf(v);
            }
        }
}

// ---------------- sum of V over keys, per (b,h,d) — vectorized ----------------
__global__ __launch_bounds__(256) void sumv_kernel(const unsigned short* __restrict__ Vb,
                                                   float* __restrict__ sumV) {
    __shared__ float r[32][HDIM];
    const int bh = blockIdx.x;
    const int b = bh / NHEADS, h = bh % NHEADS;
    const int dg = (threadIdx.x & 7) * 8;
    const int r0 = threadIdx.x >> 3;
    float acc[8] = {};
    const unsigned short* vp = Vb + (size_t)(b * SEQ) * EMBED + h * HDIM + dg;
    for (int j = r0; j < SEQ; j += 32) {
        short8 v = *reinterpret_cast<const short8*>(vp + (size_t)j * EMBED);
#pragma unroll
        for (int e = 0; e < 8; ++e)
            acc[e] += bf2f(((const unsigned short*)&v)[e]);
    }
#pragma unroll
    for (int e = 0; e < 8; ++e) r[r0][dg + e] = acc[e];
    __syncthreads();
    if (threadIdx.x < HDIM) {
        float s = 0.f;
#pragma unroll
        for (int i = 0; i < 32; ++i) s += r[i][threadIdx.x];
        sumV[bh * HDIM + threadIdx.x] = s;
    }
}

// ---------------- MFMA-tile attention: 32 q-rows per block ----------------
// Writes only the near-band segments [c-1, c+1]; far segments were filled by the QKV GEMM.
__global__ __launch_bounds__(256, 3) void attn_mfma(
    const unsigned short* __restrict__ Q,
    const unsigned short* __restrict__ Kb,
    const unsigned short* __restrict__ Vb,
    const unsigned char* __restrict__ kpm,
    const float* __restrict__ sumV,
    float* __restrict__ attn_out,
    unsigned short* __restrict__ ctx) {
    const int qt = blockIdx.x;
    const int bh = blockIdx.y;
    const int h = bh % NHEADS;
    const int b = bh / NHEADS;
    const int q0 = qt * QT;
    const int kstart = max(q0 - WIN, 0);

    __shared__ float Sf[QT][SPAD];
    __shared__ unsigned short Pb[QT][KPAD];
    __shared__ unsigned short Vt[HDIM][KPAD];

    const int tid = threadIdx.x;
    const int l = tid & 63;
    const int w = tid >> 6;
    const int fr = l & 15;
    const int ksl = (l >> 4) * 8;

    const size_t base = (size_t)(b * SEQ) * EMBED + h * HDIM;

    // ======== Phase A: scores via MFMA + Vt staging ========
    {
        const int mf = w >> 1;
        const int nt0 = (w & 1) * 5;

        const unsigned short* qrow = Q + base + (size_t)(q0 + mf * 16 + fr) * EMBED;
        short8 aq0 = *reinterpret_cast<const short8*>(qrow + ksl);
        short8 aq1 = *reinterpret_cast<const short8*>(qrow + 32 + ksl);

        f32x4 sacc[5] = {};
#pragma unroll
        for (int t = 0; t < 5; ++t) {
            int jg = kstart + (nt0 + t) * 16 + fr;
            int jc = min(jg, SEQ - 1);
            const unsigned short* krow = Kb + base + (size_t)jc * EMBED;
            short8 b0 = *reinterpret_cast<const short8*>(krow + ksl);
            short8 b1 = *reinterpret_cast<const short8*>(krow + 32 + ksl);
            sacc[t] = __builtin_amdgcn_mfma_f32_16x16x32_bf16(aq0, b0, sacc[t], 0, 0, 0);
            sacc[t] = __builtin_amdgcn_mfma_f32_16x16x32_bf16(aq1, b1, sacc[t], 0, 0, 0);
        }

#pragma unroll
        for (int t = 0; t < 5; ++t) {
            int col = (nt0 + t) * 16 + fr;
            int jg = kstart + col;
            bool jvalid = (jg < SEQ);
            bool mk = jvalid && kpm[b * SEQ + jg];
#pragma unroll
            for (int r = 0; r < 4; ++r) {
                int rowl = mf * 16 + (l >> 4) * 4 + r;
                int qi = q0 + rowl;
                float s = sacc[t][r] * 0.125f;
                if (mk) s = -10000.f;
                int dd = qi - jg;
                if (!jvalid || dd > WIN || dd < -WIN) s = -1e30f;
                Sf[rowl][col] = s;
            }
        }

        // Vt staging (vectorized): 16B global loads, transposed LDS writes
#pragma unroll
        for (int pass = 0; pass < 5; ++pass) {
            int jrel = pass * 32 + (tid >> 3);
            int jg = kstart + jrel;
            int dg = (tid & 7) * 8;
            short8 v = {};
            if (jg < SEQ)
                v = *reinterpret_cast<const short8*>(Vb + base + (size_t)jg * EMBED + dg);
#pragma unroll
            for (int e = 0; e < 8; ++e)
                Vt[dg + e][jrel] = ((const unsigned short*)&v)[e];
        }
    }
    __syncthreads();

    // ======== Phase B: row softmax (8 threads per row) ========
    {
        const int row = tid >> 3;
        const int cg = tid & 7;
        float e[KP / 8];
        float m = -1e30f;
#pragma unroll
        for (int i = 0; i < KP / 8; ++i) {
            float s = Sf[row][cg + i * 8];
            e[i] = s;
            m = fmaxf(m, s);
        }
#pragma unroll
        for (int off = 1; off < 8; off <<= 1) m = fmaxf(m, __shfl_xor(m, off));
        float sum = 0.f;
#pragma unroll
        for (int i = 0; i < KP / 8; ++i) {
            e[i] = __expf(e[i] - m);
            sum += e[i];
        }
#pragma unroll
        for (int off = 1; off < 8; off <<= 1) sum += __shfl_xor(sum, off);
        float inv = 1.f / sum;
#pragma unroll
        for (int i = 0; i < KP / 8; ++i) {
            float p = e[i] * inv;
            int col = cg + i * 8;
            Sf[row][col] = p;
            Pb[row][col] = f2bf(p);
        }
    }
    __syncthreads();

    // ======== Phase D: near-band segments only ([c-1, c+1]) ========
    {
#pragma unroll
        for (int rr = 0; rr < QT / 4; ++rr) {
            int row = w * (QT / 4) + rr;
            int qi = q0 + row;
            int blo = max(qi - WIN, 0);
            int bhi = min(qi + WIN, SEQ - 1);
            int c = qi >> 8;
            int slo = max(c - 1, 0);
            int shi = min(c + 1, 7);
            float* __restrict__ orow = attn_out + ((size_t)bh * SEQ + qi) * SEQ;
            for (int seg = slo; seg <= shi; ++seg) {
                int c0 = seg * 256 + l * 4;
                f32x4 v = {1e-6f, 1e-6f, 1e-6f, 1e-6f};
                if (c0 + 3 >= blo && c0 <= bhi) {
#pragma unroll
                    for (int e = 0; e < 4; ++e) {
                        int cc = c0 + e;
                        if (cc >= blo && cc <= bhi) v[e] = Sf[row][cc - kstart] + 1e-6f;
                    }
                }
                __builtin_nontemporal_store(v, reinterpret_cast<f32x4*>(orow + c0));
            }
        }
    }

    // ======== Phase C: PV via MFMA -> ctx ========
    {
        const int mf = w >> 1;
        const int nfb = (w & 1) * 2;
        f32x4 oacc[2] = {};
#pragma unroll
        for (int kk = 0; kk < KP / 32; ++kk) {
            short8 a = *reinterpret_cast<const short8*>(&Pb[mf * 16 + fr][kk * 32 + ksl]);
#pragma unroll
            for (int n2 = 0; n2 < 2; ++n2) {
                short8 bv = *reinterpret_cast<const short8*>(&Vt[(nfb + n2) * 16 + fr][kk * 32 + ksl]);
                oacc[n2] = __builtin_amdgcn_mfma_f32_16x16x32_bf16(a, bv, oacc[n2], 0, 0, 0);
            }
        }
#pragma unroll
        for (int n2 = 0; n2 < 2; ++n2) {
            int d = (nfb + n2) * 16 + fr;
            float sv = 1e-6f * sumV[bh * HDIM + d];
#pragma unroll
            for (int r = 0; r < 4; ++r) {
                int rowl = mf * 16 + (l >> 4) * 4 + r;
                ctx[base + (size_t)(q0 + rowl) * EMBED + d] = f2bf(oacc[n2][r] + sv);
            }
        }
    }
}

// ---------------- host ----------------
extern "C" void kernel_launch(void* const* d_in, const int* in_sizes, int n_in,
                              void* d_out, int out_size, void* d_ws, size_t ws_size,
                              hipStream_t stream) {
    const float* q_in = (const float*)d_in[0];
    const float* k_in = (const float*)d_in[1];
    const float* v_in = (const float*)d_in[2];
    const unsigned char* kpm = (const unsigned char*)d_in[3];
    const float* Wq = (const float*)d_in[4];
    const float* bq = (const float*)d_in[5];
    const float* Wk = (const float*)d_in[6];
    const float* bk = (const float*)d_in[7];
    const float* Wv = (const float*)d_in[8];
    const float* bv = (const float*)d_in[9];
    const float* Wo = (const float*)d_in[10];
    const float* bo = (const float*)d_in[11];

    char* ws = (char*)d_ws;
    size_t off = 0;
    auto alloc = [&](size_t bytes) {
        void* p = ws + off;
        off += (bytes + 255) & ~255ULL;
        return p;
    };
    const size_t XB = (size_t)MROWS * EMBED * 2;
    const size_t WB = (size_t)EMBED * EMBED * 2;
    unsigned short* xq = (unsigned short*)alloc(XB);
    unsigned short* xk = (unsigned short*)alloc(XB);
    unsigned short* xv = (unsigned short*)alloc(XB);
    unsigned short* wqb = (unsigned short*)alloc(WB);
    unsigned short* wkb = (unsigned short*)alloc(WB);
    unsigned short* wvb = (unsigned short*)alloc(WB);
    unsigned short* wob = (unsigned short*)alloc(WB);
    unsigned short* Qb = (unsigned short*)alloc(XB);
    unsigned short* Kb = (unsigned short*)alloc(XB);
    unsigned short* Vb = (unsigned short*)alloc(XB);
    unsigned short* ctx = (unsigned short*)alloc(XB);
    float* sumV = (float*)alloc((size_t)NBH * HDIM * 4);

    float* out0 = (float*)d_out;
    float* attn_out = out0 + (size_t)MROWS * EMBED;

    // ---- one fused conversion launch ----
    {
        CvtArgs ca;
        const float* srcs[7] = {q_in, k_in, v_in, Wq, Wk, Wv, Wo};
        unsigned short* dsts[7] = {xq, xk, xv, wqb, wkb, wvb, wob};
        int bacc = 0;
        for (int s = 0; s < 7; ++s) {
            ca.src[s] = srcs[s];
            ca.dst[s] = dsts[s];
            ca.n4[s] = (s < 3) ? (MROWS * EMBED / 4) : (EMBED * EMBED / 4);
            ca.bstart[s] = bacc;
            bacc += (ca.n4[s] + 255) / 256;
        }
        ca.bstart[7] = bacc;
        cvt_all<<<dim3(bacc), dim3(256), 0, stream>>>(ca);
    }

    // QKV projections + far-band attn filler stream
    {
        GArgs ga;
        ga.A[0] = xq;  ga.A[1] = xk;  ga.A[2] = xv;
        ga.Bm[0] = wqb; ga.Bm[1] = wkb; ga.Bm[2] = wvb;
        ga.bias[0] = bq; ga.bias[1] = bk; ga.bias[2] = bv;
        ga.C[0] = Qb; ga.C[1] = Kb; ga.C[2] = Vb;
        ga.fill_out = attn_out;
        gemm_nt<0, 1><<<dim3(EMBED / 128, MROWS / 128, 3), dim3(256), 0, stream>>>(
            ga, MROWS, EMBED, EMBED);
    }

    sumv_kernel<<<dim3(NBH), dim3(256), 0, stream>>>(Vb, sumV);

    attn_mfma<<<dim3(SEQ / QT, NBH), dim3(256), 0, stream>>>(
        Qb, Kb, Vb, kpm, sumV, attn_out, ctx);

    // output projection -> fp32 out
    {
        GArgs ga;
        ga.A[0] = ctx;  ga.A[1] = ctx;  ga.A[2] = ctx;
        ga.Bm[0] = wob; ga.Bm[1] = wob; ga.Bm[2] = wob;
        ga.bias[0] = bo; ga.bias[1] = bo; ga.bias[2] = bo;
        ga.C[0] = out0; ga.C[1] = out0; ga.C[2] = out0;
        ga.fill_out = nullptr;
        gemm_nt<1, 0><<<dim3(EMBED / 128, MROWS / 128, 1), dim3(256), 0, stream>>>(
            ga, MROWS, EMBED, EMBED);
    }
}

// Round 11
// 166.234 us; speedup vs baseline: 1.0790x; 1.0790x over previous
//
#include <hip/hip_runtime.h>
#include <hip/hip_bf16.h>

#define EMBED 768
#define NHEADS 12
#define HDIM 64
#define WIN 64
#define BATCH 2
#define SEQ 2048
#define MROWS (BATCH*SEQ)      // 4096
#define NBH (BATCH*NHEADS)     // 24
#define QT 32                  // q rows per attn block
#define KP 160                 // key panel width
#define KPAD 168               // padded LDS cols (bf16 arrays)
#define SPAD 164               // f32 score row stride

typedef __attribute__((ext_vector_type(8))) short short8;
typedef __attribute__((ext_vector_type(4))) float f32x4;

__device__ __forceinline__ float bf2f(unsigned short u) {
    union { unsigned int i; float f; } z;
    z.i = ((unsigned int)u) << 16;
    return z.f;
}
__device__ __forceinline__ unsigned short f2bf(float f) {
    __hip_bfloat16 h = __float2bfloat16(f);
    return *reinterpret_cast<unsigned short*>(&h);
}

// async global->LDS, 16 B per lane; LDS dest must be waveBase + lane*16
__device__ __forceinline__ void gload16(const unsigned short* g, unsigned short* l) {
    __builtin_amdgcn_global_load_lds(
        (const __attribute__((address_space(1))) unsigned int*)g,
        (__attribute__((address_space(3))) unsigned int*)l,
        16, 0, 0);
}

// ---------------- fused fp32 -> bf16 conversion (7 segments, 1 launch) ----------------
struct CvtArgs {
    const float* src[7];
    unsigned short* dst[7];
    int n4[7];
    int bstart[8];
};

__global__ __launch_bounds__(256) void cvt_all(CvtArgs ca) {
    int bid = blockIdx.x;
    int seg = 0;
#pragma unroll
    for (int s = 0; s < 6; ++s)
        if (bid >= ca.bstart[s + 1]) seg = s + 1;
    int i = (bid - ca.bstart[seg]) * 256 + threadIdx.x;
    if (i < ca.n4[seg]) {
        float4 v = reinterpret_cast<const float4*>(ca.src[seg])[i];
        ushort4 o;
        o.x = f2bf(v.x); o.y = f2bf(v.y); o.z = f2bf(v.z); o.w = f2bf(v.w);
        reinterpret_cast<ushort4*>(ca.dst[seg])[i] = o;
    }
}

// ---------------- bf16 NT GEMM: C[M,N] = A[M,K] * B[N,K]^T + bias ----------------
// XCD-aware swizzle: each XCD owns complete (z, bm) A-panels across all bn tiles,
// so a panel is fetched into one XCD's L2 once instead of gridDim.x times.
struct GArgs {
    const unsigned short* A[3];
    const unsigned short* Bm[3];
    const float* bias[3];
    void* C[3];
};

template<int F32OUT>
__global__ __launch_bounds__(256) void gemm_nt(GArgs ga, int M, int N, int K) {
    // ---- bijective XCD remap: requires (gridDim.y*gridDim.z) % 8 == 0 ----
    const int NPANEL = gridDim.y * gridDim.z;          // A panels total
    const int flat = (blockIdx.z * gridDim.y + blockIdx.y) * gridDim.x + blockIdx.x;
    const int xcd = flat & 7;
    const int j = flat >> 3;
    const int panel = xcd * (NPANEL >> 3) + j / gridDim.x;
    const int z = panel / gridDim.y;
    const int bm = (panel % gridDim.y) * 128;
    const int bn = (j % gridDim.x) * 128;

    const unsigned short* __restrict__ A  = ga.A[z];
    const unsigned short* __restrict__ Bm = ga.Bm[z];
    const float* __restrict__ bias = ga.bias[z];

    __shared__ unsigned short As[128 * 32];   // linear [128][32]
    __shared__ unsigned short Bs[128 * 32];

    const int tid = threadIdx.x;
    const int lane = tid & 63;
    const int wid = tid >> 6;
    const int wm = wid >> 1, wn = wid & 1;

    f32x4 acc[4][4] = {};

    const int fr = lane & 15;
    const int krow = (lane >> 4) * 8;

    for (int k0 = 0; k0 < K; k0 += 32) {
#pragma unroll
        for (int it = 0; it < 2; ++it) {
            int idx = it * 256 + tid;
            int r = idx >> 2;
            int c = (idx & 3) * 8;
            gload16(A + (size_t)(bm + r) * K + k0 + c, &As[idx * 8]);
            gload16(Bm + (size_t)(bn + r) * K + k0 + c, &Bs[idx * 8]);
        }
        __syncthreads();

        short8 af[4], bfv[4];
#pragma unroll
        for (int mf = 0; mf < 4; ++mf)
            af[mf] = *reinterpret_cast<const short8*>(&As[(wm * 64 + mf * 16 + fr) * 32 + krow]);
#pragma unroll
        for (int nf = 0; nf < 4; ++nf)
            bfv[nf] = *reinterpret_cast<const short8*>(&Bs[(wn * 64 + nf * 16 + fr) * 32 + krow]);
#pragma unroll
        for (int mf = 0; mf < 4; ++mf)
#pragma unroll
            for (int nf = 0; nf < 4; ++nf)
                acc[mf][nf] = __builtin_amdgcn_mfma_f32_16x16x32_bf16(
                    af[mf], bfv[nf], acc[mf][nf], 0, 0, 0);
        __syncthreads();
    }

    const int fq = lane >> 4;
#pragma unroll
    for (int mf = 0; mf < 4; ++mf)
#pragma unroll
        for (int nf = 0; nf < 4; ++nf) {
            int col = bn + wn * 64 + nf * 16 + fr;
            float bv = bias[col];
#pragma unroll
            for (int r = 0; r < 4; ++r) {
                int row = bm + wm * 64 + mf * 16 + fq * 4 + r;
                float v = acc[mf][nf][r] + bv;
                if (F32OUT)
                    reinterpret_cast<float*>(ga.C[z])[(size_t)row * N + col] = v;
                else
                    reinterpret_cast<unsigned short*>(ga.C[z])[(size_t)row * N + col] = f2bf(v);
            }
        }
}

// ---------------- sum of V over keys, per (b,h,d) — vectorized ----------------
__global__ __launch_bounds__(256) void sumv_kernel(const unsigned short* __restrict__ Vb,
                                                   float* __restrict__ sumV) {
    __shared__ float r[32][HDIM];
    const int bh = blockIdx.x;
    const int b = bh / NHEADS, h = bh % NHEADS;
    const int dg = (threadIdx.x & 7) * 8;
    const int r0 = threadIdx.x >> 3;
    float acc[8] = {};
    const unsigned short* vp = Vb + (size_t)(b * SEQ) * EMBED + h * HDIM + dg;
    for (int j = r0; j < SEQ; j += 32) {
        short8 v = *reinterpret_cast<const short8*>(vp + (size_t)j * EMBED);
#pragma unroll
        for (int e = 0; e < 8; ++e)
            acc[e] += bf2f(((const unsigned short*)&v)[e]);
    }
#pragma unroll
    for (int e = 0; e < 8; ++e) r[r0][dg + e] = acc[e];
    __syncthreads();
    if (threadIdx.x < HDIM) {
        float s = 0.f;
#pragma unroll
        for (int i = 0; i < 32; ++i) s += r[i][threadIdx.x];
        sumV[bh * HDIM + threadIdx.x] = s;
    }
}

// ---------------- MFMA-tile attention: 32 q-rows per block ----------------
// Phase 0: filler NT stores at entry (overlap with compute).
// XCD swizzle: each XCD owns contiguous (bh, qt) runs -> K/V panel L2 reuse.
__global__ __launch_bounds__(256, 3) void attn_mfma(
    const unsigned short* __restrict__ Q,
    const unsigned short* __restrict__ Kb,
    const unsigned short* __restrict__ Vb,
    const unsigned char* __restrict__ kpm,
    const float* __restrict__ sumV,
    float* __restrict__ attn_out,
    unsigned short* __restrict__ ctx) {
    // 1536 blocks -> xcd chunk of 192 contiguous (bh,qt) pairs
    const int flat = blockIdx.y * gridDim.x + blockIdx.x;
    const int g2 = (flat & 7) * 192 + (flat >> 3);
    const int bh = g2 >> 6;
    const int qt = g2 & 63;
    const int h = bh % NHEADS;
    const int b = bh / NHEADS;
    const int q0 = qt * QT;
    const int kstart = max(q0 - WIN, 0);

    __shared__ float Sf[QT][SPAD];
    __shared__ unsigned short Pb[QT][KPAD];
    __shared__ unsigned short Vt[HDIM][KPAD];

    const int tid = threadIdx.x;
    const int l = tid & 63;
    const int w = tid >> 6;
    const int fr = l & 15;
    const int ksl = (l >> 4) * 8;

    const size_t base = (size_t)(b * SEQ) * EMBED + h * HDIM;

    // ======== Phase 0: filler stores for non-band segments (overlap w/ compute) ====
    {
        const f32x4 fill = {1e-6f, 1e-6f, 1e-6f, 1e-6f};
#pragma unroll
        for (int rr = 0; rr < QT / 4; ++rr) {
            int row = w * (QT / 4) + rr;
            int qi = q0 + row;
            int blo = max(qi - WIN, 0);
            int bhi = min(qi + WIN, SEQ - 1);
            float* __restrict__ orow = attn_out + ((size_t)bh * SEQ + qi) * SEQ;
#pragma unroll
            for (int seg = 0; seg < SEQ / 256; ++seg) {
                if (seg * 256 + 255 >= blo && seg * 256 <= bhi) continue;
                __builtin_nontemporal_store(
                    fill, reinterpret_cast<f32x4*>(orow + seg * 256 + l * 4));
            }
        }
    }

    // ======== Phase A: scores via MFMA + Vt staging ========
    {
        const int mf = w >> 1;
        const int nt0 = (w & 1) * 5;

        const unsigned short* qrow = Q + base + (size_t)(q0 + mf * 16 + fr) * EMBED;
        short8 aq0 = *reinterpret_cast<const short8*>(qrow + ksl);
        short8 aq1 = *reinterpret_cast<const short8*>(qrow + 32 + ksl);

        f32x4 sacc[5] = {};
#pragma unroll
        for (int t = 0; t < 5; ++t) {
            int jg = kstart + (nt0 + t) * 16 + fr;
            int jc = min(jg, SEQ - 1);
            const unsigned short* krow = Kb + base + (size_t)jc * EMBED;
            short8 b0 = *reinterpret_cast<const short8*>(krow + ksl);
            short8 b1 = *reinterpret_cast<const short8*>(krow + 32 + ksl);
            sacc[t] = __builtin_amdgcn_mfma_f32_16x16x32_bf16(aq0, b0, sacc[t], 0, 0, 0);
            sacc[t] = __builtin_amdgcn_mfma_f32_16x16x32_bf16(aq1, b1, sacc[t], 0, 0, 0);
        }

#pragma unroll
        for (int t = 0; t < 5; ++t) {
            int col = (nt0 + t) * 16 + fr;
            int jg = kstart + col;
            bool jvalid = (jg < SEQ);
            bool mk = jvalid && kpm[b * SEQ + jg];
#pragma unroll
            for (int r = 0; r < 4; ++r) {
                int rowl = mf * 16 + (l >> 4) * 4 + r;
                int qi = q0 + rowl;
                float s = sacc[t][r] * 0.125f;
                if (mk) s = -10000.f;
                int dd = qi - jg;
                if (!jvalid || dd > WIN || dd < -WIN) s = -1e30f;
                Sf[rowl][col] = s;
            }
        }

        // Vt staging (vectorized): 16B global loads, transposed LDS writes
#pragma unroll
        for (int pass = 0; pass < 5; ++pass) {
            int jrel = pass * 32 + (tid >> 3);
            int jg = kstart + jrel;
            int dg = (tid & 7) * 8;
            short8 v = {};
            if (jg < SEQ)
                v = *reinterpret_cast<const short8*>(Vb + base + (size_t)jg * EMBED + dg);
#pragma unroll
            for (int e = 0; e < 8; ++e)
                Vt[dg + e][jrel] = ((const unsigned short*)&v)[e];
        }
    }
    __syncthreads();

    // ======== Phase B: row softmax (8 threads per row) ========
    {
        const int row = tid >> 3;
        const int cg = tid & 7;
        float e[KP / 8];
        float m = -1e30f;
#pragma unroll
        for (int i = 0; i < KP / 8; ++i) {
            float s = Sf[row][cg + i * 8];
            e[i] = s;
            m = fmaxf(m, s);
        }
#pragma unroll
        for (int off = 1; off < 8; off <<= 1) m = fmaxf(m, __shfl_xor(m, off));
        float sum = 0.f;
#pragma unroll
        for (int i = 0; i < KP / 8; ++i) {
            e[i] = __expf(e[i] - m);
            sum += e[i];
        }
#pragma unroll
        for (int off = 1; off < 8; off <<= 1) sum += __shfl_xor(sum, off);
        float inv = 1.f / sum;
#pragma unroll
        for (int i = 0; i < KP / 8; ++i) {
            float p = e[i] * inv;
            int col = cg + i * 8;
            Sf[row][col] = p;
            Pb[row][col] = f2bf(p);
        }
    }
    __syncthreads();

    // ======== Phase D: band-straddling segments only ========
    {
#pragma unroll
        for (int rr = 0; rr < QT / 4; ++rr) {
            int row = w * (QT / 4) + rr;
            int qi = q0 + row;
            int blo = max(qi - WIN, 0);
            int bhi = min(qi + WIN, SEQ - 1);
            float* __restrict__ orow = attn_out + ((size_t)bh * SEQ + qi) * SEQ;
            int slo = blo >> 8;
            int shi = bhi >> 8;
            for (int seg = slo; seg <= shi; ++seg) {
                int c0 = seg * 256 + l * 4;
                f32x4 v = {1e-6f, 1e-6f, 1e-6f, 1e-6f};
#pragma unroll
                for (int e = 0; e < 4; ++e) {
                    int c = c0 + e;
                    if (c >= blo && c <= bhi) v[e] = Sf[row][c - kstart] + 1e-6f;
                }
                __builtin_nontemporal_store(v, reinterpret_cast<f32x4*>(orow + c0));
            }
        }
    }

    // ======== Phase C: PV via MFMA -> ctx ========
    {
        const int mf = w >> 1;
        const int nfb = (w & 1) * 2;
        f32x4 oacc[2] = {};
#pragma unroll
        for (int kk = 0; kk < KP / 32; ++kk) {
            short8 a = *reinterpret_cast<const short8*>(&Pb[mf * 16 + fr][kk * 32 + ksl]);
#pragma unroll
            for (int n2 = 0; n2 < 2; ++n2) {
                short8 bv = *reinterpret_cast<const short8*>(&Vt[(nfb + n2) * 16 + fr][kk * 32 + ksl]);
                oacc[n2] = __builtin_amdgcn_mfma_f32_16x16x32_bf16(a, bv, oacc[n2], 0, 0, 0);
            }
        }
#pragma unroll
        for (int n2 = 0; n2 < 2; ++n2) {
            int d = (nfb + n2) * 16 + fr;
            float sv = 1e-6f * sumV[bh * HDIM + d];
#pragma unroll
            for (int r = 0; r < 4; ++r) {
                int rowl = mf * 16 + (l >> 4) * 4 + r;
                ctx[base + (size_t)(q0 + rowl) * EMBED + d] = f2bf(oacc[n2][r] + sv);
            }
        }
    }
}

// ---------------- host ----------------
extern "C" void kernel_launch(void* const* d_in, const int* in_sizes, int n_in,
                              void* d_out, int out_size, void* d_ws, size_t ws_size,
                              hipStream_t stream) {
    const float* q_in = (const float*)d_in[0];
    const float* k_in = (const float*)d_in[1];
    const float* v_in = (const float*)d_in[2];
    const unsigned char* kpm = (const unsigned char*)d_in[3];
    const float* Wq = (const float*)d_in[4];
    const float* bq = (const float*)d_in[5];
    const float* Wk = (const float*)d_in[6];
    const float* bk = (const float*)d_in[7];
    const float* Wv = (const float*)d_in[8];
    const float* bv = (const float*)d_in[9];
    const float* Wo = (const float*)d_in[10];
    const float* bo = (const float*)d_in[11];

    char* ws = (char*)d_ws;
    size_t off = 0;
    auto alloc = [&](size_t bytes) {
        void* p = ws + off;
        off += (bytes + 255) & ~255ULL;
        return p;
    };
    const size_t XB = (size_t)MROWS * EMBED * 2;
    const size_t WB = (size_t)EMBED * EMBED * 2;
    unsigned short* xq = (unsigned short*)alloc(XB);
    unsigned short* xk = (unsigned short*)alloc(XB);
    unsigned short* xv = (unsigned short*)alloc(XB);
    unsigned short* wqb = (unsigned short*)alloc(WB);
    unsigned short* wkb = (unsigned short*)alloc(WB);
    unsigned short* wvb = (unsigned short*)alloc(WB);
    unsigned short* wob = (unsigned short*)alloc(WB);
    unsigned short* Qb = (unsigned short*)alloc(XB);
    unsigned short* Kb = (unsigned short*)alloc(XB);
    unsigned short* Vb = (unsigned short*)alloc(XB);
    unsigned short* ctx = (unsigned short*)alloc(XB);
    float* sumV = (float*)alloc((size_t)NBH * HDIM * 4);

    float* out0 = (float*)d_out;
    float* attn_out = out0 + (size_t)MROWS * EMBED;

    // ---- one fused conversion launch ----
    {
        CvtArgs ca;
        const float* srcs[7] = {q_in, k_in, v_in, Wq, Wk, Wv, Wo};
        unsigned short* dsts[7] = {xq, xk, xv, wqb, wkb, wvb, wob};
        int bacc = 0;
        for (int s = 0; s < 7; ++s) {
            ca.src[s] = srcs[s];
            ca.dst[s] = dsts[s];
            ca.n4[s] = (s < 3) ? (MROWS * EMBED / 4) : (EMBED * EMBED / 4);
            ca.bstart[s] = bacc;
            bacc += (ca.n4[s] + 255) / 256;
        }
        ca.bstart[7] = bacc;
        cvt_all<<<dim3(bacc), dim3(256), 0, stream>>>(ca);
    }

    // QKV projections (XCD-swizzled)
    {
        GArgs ga;
        ga.A[0] = xq;  ga.A[1] = xk;  ga.A[2] = xv;
        ga.Bm[0] = wqb; ga.Bm[1] = wkb; ga.Bm[2] = wvb;
        ga.bias[0] = bq; ga.bias[1] = bk; ga.bias[2] = bv;
        ga.C[0] = Qb; ga.C[1] = Kb; ga.C[2] = Vb;
        gemm_nt<0><<<dim3(EMBED / 128, MROWS / 128, 3), dim3(256), 0, stream>>>(
            ga, MROWS, EMBED, EMBED);
    }

    sumv_kernel<<<dim3(NBH), dim3(256), 0, stream>>>(Vb, sumV);

    attn_mfma<<<dim3(SEQ / QT, NBH), dim3(256), 0, stream>>>(
        Qb, Kb, Vb, kpm, sumV, attn_out, ctx);

    // output projection -> fp32 out (XCD-swizzled)
    {
        GArgs ga;
        ga.A[0] = ctx;  ga.A[1] = ctx;  ga.A[2] = ctx;
        ga.Bm[0] = wob; ga.Bm[1] = wob; ga.Bm[2] = wob;
        ga.bias[0] = bo; ga.bias[1] = bo; ga.bias[2] = bo;
        ga.C[0] = out0; ga.C[1] = out0; ga.C[2] = out0;
        gemm_nt<1><<<dim3(EMBED / 128, MROWS / 128, 1), dim3(256), 0, stream>>>(
            ga, MROWS, EMBED, EMBED);
    }
}

// Round 12
// 159.891 us; speedup vs baseline: 1.1218x; 1.0397x over previous
//
#include <hip/hip_runtime.h>
#include <hip/hip_bf16.h>

#define EMBED 768
#define NHEADS 12
#define HDIM 64
#define WIN 64
#define BATCH 2
#define SEQ 2048
#define MROWS (BATCH*SEQ)      // 4096
#define NBH (BATCH*NHEADS)     // 24
#define QT 32                  // q rows per attn block
#define KP 160                 // key panel width
#define KPAD 168               // padded LDS cols (bf16 arrays)
#define SPAD 164               // f32 score row stride

typedef __attribute__((ext_vector_type(8))) short short8;
typedef __attribute__((ext_vector_type(4))) float f32x4;

__device__ __forceinline__ float bf2f(unsigned short u) {
    union { unsigned int i; float f; } z;
    z.i = ((unsigned int)u) << 16;
    return z.f;
}
__device__ __forceinline__ unsigned short f2bf(float f) {
    __hip_bfloat16 h = __float2bfloat16(f);
    return *reinterpret_cast<unsigned short*>(&h);
}

// async global->LDS, 16 B per lane; LDS dest must be waveBase + lane*16
__device__ __forceinline__ void gload16(const void* g, void* l) {
    __builtin_amdgcn_global_load_lds(
        (const __attribute__((address_space(1))) unsigned int*)g,
        (__attribute__((address_space(3))) unsigned int*)l,
        16, 0, 0);
}

// ---------------- fp32 -> bf16 conversion for the 4 weight matrices ----------------
struct CvtArgs {
    const float* src[4];
    unsigned short* dst[4];
};

__global__ __launch_bounds__(256) void cvt_w(CvtArgs ca) {
    const int n4 = EMBED * EMBED / 4;              // 147456
    const int bper = (n4 + 255) / 256;             // 576 blocks per segment
    int seg = blockIdx.x / bper;
    int i = (blockIdx.x - seg * bper) * 256 + threadIdx.x;
    if (i < n4) {
        float4 v = reinterpret_cast<const float4*>(ca.src[seg])[i];
        ushort4 o;
        o.x = f2bf(v.x); o.y = f2bf(v.y); o.z = f2bf(v.z); o.w = f2bf(v.w);
        reinterpret_cast<ushort4*>(ca.dst[seg])[i] = o;
    }
}

// ---------------- bf16 NT GEMM: C[M,N] = A[M,K] * B[N,K]^T + bias ----------------
// XCD-aware swizzle (r11). F32A=1: A is fp32 staged async via global_load_lds with
// XOR-swizzled source chunks (rule 21: linear LDS dest, permuted global src,
// un-permuted LDS read); converted to bf16 at fragment-read time (identical rounding).
struct GArgs {
    const void* A[3];
    const unsigned short* Bm[3];
    const float* bias[3];
    void* C[3];
};

template<int F32OUT, int F32A>
__global__ __launch_bounds__(256) void gemm_nt(GArgs ga, int M, int N, int K) {
    // ---- bijective XCD remap: requires (gridDim.y*gridDim.z) % 8 == 0 ----
    const int NPANEL = gridDim.y * gridDim.z;
    const int flat = (blockIdx.z * gridDim.y + blockIdx.y) * gridDim.x + blockIdx.x;
    const int xcd = flat & 7;
    const int j = flat >> 3;
    const int panel = xcd * (NPANEL >> 3) + j / gridDim.x;
    const int z = panel / gridDim.y;
    const int bm = (panel % gridDim.y) * 128;
    const int bn = (j % gridDim.x) * 128;

    const unsigned short* __restrict__ Bm = ga.Bm[z];
    const float* __restrict__ bias = ga.bias[z];

    __shared__ alignas(16) unsigned char AsRaw[F32A ? 128 * 32 * 4 : 128 * 32 * 2];
    __shared__ unsigned short Bs[128 * 32];

    const int tid = threadIdx.x;
    const int lane = tid & 63;
    const int wid = tid >> 6;
    const int wm = wid >> 1, wn = wid & 1;

    f32x4 acc[4][4] = {};

    const int fr = lane & 15;
    const int krow = (lane >> 4) * 8;

    for (int k0 = 0; k0 < K; k0 += 32) {
        if (F32A) {
            const float* Af = (const float*)ga.A[z];
            float* AsF = (float*)AsRaw;
            // 1024 chunks of 4 f32; source chunk col XOR-permuted by row (bank fix)
#pragma unroll
            for (int it = 0; it < 4; ++it) {
                int idx = it * 256 + tid;
                int r = idx >> 3;
                int cc = idx & 7;
                int gcc = cc ^ (r & 7);
                gload16(Af + (size_t)(bm + r) * K + k0 + gcc * 4, &AsF[idx * 4]);
            }
        } else {
            const unsigned short* Ab = (const unsigned short*)ga.A[z];
#pragma unroll
            for (int it = 0; it < 2; ++it) {
                int idx = it * 256 + tid;
                int r = idx >> 2;
                int c = (idx & 3) * 8;
                gload16(Ab + (size_t)(bm + r) * K + k0 + c,
                        (unsigned short*)AsRaw + idx * 8);
            }
        }
#pragma unroll
        for (int it = 0; it < 2; ++it) {
            int idx = it * 256 + tid;
            int r = idx >> 2;
            int c = (idx & 3) * 8;
            gload16(Bm + (size_t)(bn + r) * K + k0 + c, &Bs[idx * 8]);
        }
        __syncthreads();

        short8 af[4], bfv[4];
#pragma unroll
        for (int mf = 0; mf < 4; ++mf) {
            int r = wm * 64 + mf * 16 + fr;
            if (F32A) {
                const float* AsF = (const float*)AsRaw;
                int kc0 = (lane >> 4) * 2;
                int s0 = kc0 ^ (r & 7);
                f32x4 v0 = *reinterpret_cast<const f32x4*>(&AsF[(r * 8 + s0) * 4]);
                f32x4 v1 = *reinterpret_cast<const f32x4*>(&AsF[(r * 8 + (s0 ^ 1)) * 4]);
                unsigned short* ou = reinterpret_cast<unsigned short*>(&af[mf]);
                ou[0] = f2bf(v0[0]); ou[1] = f2bf(v0[1]);
                ou[2] = f2bf(v0[2]); ou[3] = f2bf(v0[3]);
                ou[4] = f2bf(v1[0]); ou[5] = f2bf(v1[1]);
                ou[6] = f2bf(v1[2]); ou[7] = f2bf(v1[3]);
            } else {
                af[mf] = *reinterpret_cast<const short8*>(
                    (const unsigned short*)AsRaw + r * 32 + krow);
            }
        }
#pragma unroll
        for (int nf = 0; nf < 4; ++nf)
            bfv[nf] = *reinterpret_cast<const short8*>(&Bs[(wn * 64 + nf * 16 + fr) * 32 + krow]);
#pragma unroll
        for (int mf = 0; mf < 4; ++mf)
#pragma unroll
            for (int nf = 0; nf < 4; ++nf)
                acc[mf][nf] = __builtin_amdgcn_mfma_f32_16x16x32_bf16(
                    af[mf], bfv[nf], acc[mf][nf], 0, 0, 0);
        __syncthreads();
    }

    const int fq = lane >> 4;
#pragma unroll
    for (int mf = 0; mf < 4; ++mf)
#pragma unroll
        for (int nf = 0; nf < 4; ++nf) {
            int col = bn + wn * 64 + nf * 16 + fr;
            float bv = bias[col];
#pragma unroll
            for (int r = 0; r < 4; ++r) {
                int row = bm + wm * 64 + mf * 16 + fq * 4 + r;
                float v = acc[mf][nf][r] + bv;
                if (F32OUT)
                    reinterpret_cast<float*>(ga.C[z])[(size_t)row * N + col] = v;
                else
                    reinterpret_cast<unsigned short*>(ga.C[z])[(size_t)row * N + col] = f2bf(v);
            }
        }
}

// ---------------- sum of V over keys, per (b,h,d) — vectorized ----------------
__global__ __launch_bounds__(256) void sumv_kernel(const unsigned short* __restrict__ Vb,
                                                   float* __restrict__ sumV) {
    __shared__ float r[32][HDIM];
    const int bh = blockIdx.x;
    const int b = bh / NHEADS, h = bh % NHEADS;
    const int dg = (threadIdx.x & 7) * 8;
    const int r0 = threadIdx.x >> 3;
    float acc[8] = {};
    const unsigned short* vp = Vb + (size_t)(b * SEQ) * EMBED + h * HDIM + dg;
    for (int j = r0; j < SEQ; j += 32) {
        short8 v = *reinterpret_cast<const short8*>(vp + (size_t)j * EMBED);
#pragma unroll
        for (int e = 0; e < 8; ++e)
            acc[e] += bf2f(((const unsigned short*)&v)[e]);
    }
#pragma unroll
    for (int e = 0; e < 8; ++e) r[r0][dg + e] = acc[e];
    __syncthreads();
    if (threadIdx.x < HDIM) {
        float s = 0.f;
#pragma unroll
        for (int i = 0; i < 32; ++i) s += r[i][threadIdx.x];
        sumV[bh * HDIM + threadIdx.x] = s;
    }
}

// ---------------- MFMA-tile attention: 32 q-rows per block ----------------
// Phase 0 filler stores at entry; XCD swizzle for K/V panel L2 reuse.
__global__ __launch_bounds__(256, 3) void attn_mfma(
    const unsigned short* __restrict__ Q,
    const unsigned short* __restrict__ Kb,
    const unsigned short* __restrict__ Vb,
    const unsigned char* __restrict__ kpm,
    const float* __restrict__ sumV,
    float* __restrict__ attn_out,
    unsigned short* __restrict__ ctx) {
    const int flat = blockIdx.y * gridDim.x + blockIdx.x;
    const int g2 = (flat & 7) * 192 + (flat >> 3);
    const int bh = g2 >> 6;
    const int qt = g2 & 63;
    const int h = bh % NHEADS;
    const int b = bh / NHEADS;
    const int q0 = qt * QT;
    const int kstart = max(q0 - WIN, 0);

    __shared__ float Sf[QT][SPAD];
    __shared__ unsigned short Pb[QT][KPAD];
    __shared__ unsigned short Vt[HDIM][KPAD];

    const int tid = threadIdx.x;
    const int l = tid & 63;
    const int w = tid >> 6;
    const int fr = l & 15;
    const int ksl = (l >> 4) * 8;

    const size_t base = (size_t)(b * SEQ) * EMBED + h * HDIM;

    // ======== Phase 0: filler stores for non-band segments ========
    {
        const f32x4 fill = {1e-6f, 1e-6f, 1e-6f, 1e-6f};
#pragma unroll
        for (int rr = 0; rr < QT / 4; ++rr) {
            int row = w * (QT / 4) + rr;
            int qi = q0 + row;
            int blo = max(qi - WIN, 0);
            int bhi = min(qi + WIN, SEQ - 1);
            float* __restrict__ orow = attn_out + ((size_t)bh * SEQ + qi) * SEQ;
#pragma unroll
            for (int seg = 0; seg < SEQ / 256; ++seg) {
                if (seg * 256 + 255 >= blo && seg * 256 <= bhi) continue;
                __builtin_nontemporal_store(
                    fill, reinterpret_cast<f32x4*>(orow + seg * 256 + l * 4));
            }
        }
    }

    // ======== Phase A: scores via MFMA + Vt staging ========
    {
        const int mf = w >> 1;
        const int nt0 = (w & 1) * 5;

        const unsigned short* qrow = Q + base + (size_t)(q0 + mf * 16 + fr) * EMBED;
        short8 aq0 = *reinterpret_cast<const short8*>(qrow + ksl);
        short8 aq1 = *reinterpret_cast<const short8*>(qrow + 32 + ksl);

        f32x4 sacc[5] = {};
#pragma unroll
        for (int t = 0; t < 5; ++t) {
            int jg = kstart + (nt0 + t) * 16 + fr;
            int jc = min(jg, SEQ - 1);
            const unsigned short* krow = Kb + base + (size_t)jc * EMBED;
            short8 b0 = *reinterpret_cast<const short8*>(krow + ksl);
            short8 b1 = *reinterpret_cast<const short8*>(krow + 32 + ksl);
            sacc[t] = __builtin_amdgcn_mfma_f32_16x16x32_bf16(aq0, b0, sacc[t], 0, 0, 0);
            sacc[t] = __builtin_amdgcn_mfma_f32_16x16x32_bf16(aq1, b1, sacc[t], 0, 0, 0);
        }

#pragma unroll
        for (int t = 0; t < 5; ++t) {
            int col = (nt0 + t) * 16 + fr;
            int jg = kstart + col;
            bool jvalid = (jg < SEQ);
            bool mk = jvalid && kpm[b * SEQ + jg];
#pragma unroll
            for (int r = 0; r < 4; ++r) {
                int rowl = mf * 16 + (l >> 4) * 4 + r;
                int qi = q0 + rowl;
                float s = sacc[t][r] * 0.125f;
                if (mk) s = -10000.f;
                int dd = qi - jg;
                if (!jvalid || dd > WIN || dd < -WIN) s = -1e30f;
                Sf[rowl][col] = s;
            }
        }

#pragma unroll
        for (int pass = 0; pass < 5; ++pass) {
            int jrel = pass * 32 + (tid >> 3);
            int jg = kstart + jrel;
            int dg = (tid & 7) * 8;
            short8 v = {};
            if (jg < SEQ)
                v = *reinterpret_cast<const short8*>(Vb + base + (size_t)jg * EMBED + dg);
#pragma unroll
            for (int e = 0; e < 8; ++e)
                Vt[dg + e][jrel] = ((const unsigned short*)&v)[e];
        }
    }
    __syncthreads();

    // ======== Phase B: row softmax (8 threads per row) ========
    {
        const int row = tid >> 3;
        const int cg = tid & 7;
        float e[KP / 8];
        float m = -1e30f;
#pragma unroll
        for (int i = 0; i < KP / 8; ++i) {
            float s = Sf[row][cg + i * 8];
            e[i] = s;
            m = fmaxf(m, s);
        }
#pragma unroll
        for (int off = 1; off < 8; off <<= 1) m = fmaxf(m, __shfl_xor(m, off));
        float sum = 0.f;
#pragma unroll
        for (int i = 0; i < KP / 8; ++i) {
            e[i] = __expf(e[i] - m);
            sum += e[i];
        }
#pragma unroll
        for (int off = 1; off < 8; off <<= 1) sum += __shfl_xor(sum, off);
        float inv = 1.f / sum;
#pragma unroll
        for (int i = 0; i < KP / 8; ++i) {
            float p = e[i] * inv;
            int col = cg + i * 8;
            Sf[row][col] = p;
            Pb[row][col] = f2bf(p);
        }
    }
    __syncthreads();

    // ======== Phase D: band-straddling segments only ========
    {
#pragma unroll
        for (int rr = 0; rr < QT / 4; ++rr) {
            int row = w * (QT / 4) + rr;
            int qi = q0 + row;
            int blo = max(qi - WIN, 0);
            int bhi = min(qi + WIN, SEQ - 1);
            float* __restrict__ orow = attn_out + ((size_t)bh * SEQ + qi) * SEQ;
            int slo = blo >> 8;
            int shi = bhi >> 8;
            for (int seg = slo; seg <= shi; ++seg) {
                int c0 = seg * 256 + l * 4;
                f32x4 v = {1e-6f, 1e-6f, 1e-6f, 1e-6f};
#pragma unroll
                for (int e = 0; e < 4; ++e) {
                    int c = c0 + e;
                    if (c >= blo && c <= bhi) v[e] = Sf[row][c - kstart] + 1e-6f;
                }
                __builtin_nontemporal_store(v, reinterpret_cast<f32x4*>(orow + c0));
            }
        }
    }

    // ======== Phase C: PV via MFMA -> ctx ========
    {
        const int mf = w >> 1;
        const int nfb = (w & 1) * 2;
        f32x4 oacc[2] = {};
#pragma unroll
        for (int kk = 0; kk < KP / 32; ++kk) {
            short8 a = *reinterpret_cast<const short8*>(&Pb[mf * 16 + fr][kk * 32 + ksl]);
#pragma unroll
            for (int n2 = 0; n2 < 2; ++n2) {
                short8 bv = *reinterpret_cast<const short8*>(&Vt[(nfb + n2) * 16 + fr][kk * 32 + ksl]);
                oacc[n2] = __builtin_amdgcn_mfma_f32_16x16x32_bf16(a, bv, oacc[n2], 0, 0, 0);
            }
        }
#pragma unroll
        for (int n2 = 0; n2 < 2; ++n2) {
            int d = (nfb + n2) * 16 + fr;
            float sv = 1e-6f * sumV[bh * HDIM + d];
#pragma unroll
            for (int r = 0; r < 4; ++r) {
                int rowl = mf * 16 + (l >> 4) * 4 + r;
                ctx[base + (size_t)(q0 + rowl) * EMBED + d] = f2bf(oacc[n2][r] + sv);
            }
        }
    }
}

// ---------------- host ----------------
extern "C" void kernel_launch(void* const* d_in, const int* in_sizes, int n_in,
                              void* d_out, int out_size, void* d_ws, size_t ws_size,
                              hipStream_t stream) {
    const float* q_in = (const float*)d_in[0];
    const float* k_in = (const float*)d_in[1];
    const float* v_in = (const float*)d_in[2];
    const unsigned char* kpm = (const unsigned char*)d_in[3];
    const float* Wq = (const float*)d_in[4];
    const float* bq = (const float*)d_in[5];
    const float* Wk = (const float*)d_in[6];
    const float* bk = (const float*)d_in[7];
    const float* Wv = (const float*)d_in[8];
    const float* bv = (const float*)d_in[9];
    const float* Wo = (const float*)d_in[10];
    const float* bo = (const float*)d_in[11];

    char* ws = (char*)d_ws;
    size_t off = 0;
    auto alloc = [&](size_t bytes) {
        void* p = ws + off;
        off += (bytes + 255) & ~255ULL;
        return p;
    };
    const size_t XB = (size_t)MROWS * EMBED * 2;
    const size_t WB = (size_t)EMBED * EMBED * 2;
    unsigned short* wqb = (unsigned short*)alloc(WB);
    unsigned short* wkb = (unsigned short*)alloc(WB);
    unsigned short* wvb = (unsigned short*)alloc(WB);
    unsigned short* wob = (unsigned short*)alloc(WB);
    unsigned short* Qb = (unsigned short*)alloc(XB);
    unsigned short* Kb = (unsigned short*)alloc(XB);
    unsigned short* Vb = (unsigned short*)alloc(XB);
    unsigned short* ctx = (unsigned short*)alloc(XB);
    float* sumV = (float*)alloc((size_t)NBH * HDIM * 4);

    float* out0 = (float*)d_out;
    float* attn_out = out0 + (size_t)MROWS * EMBED;

    // ---- weight conversion only (inputs converted inside QKV GEMM) ----
    {
        CvtArgs ca;
        ca.src[0] = Wq; ca.src[1] = Wk; ca.src[2] = Wv; ca.src[3] = Wo;
        ca.dst[0] = wqb; ca.dst[1] = wkb; ca.dst[2] = wvb; ca.dst[3] = wob;
        int bper = (EMBED * EMBED / 4 + 255) / 256;
        cvt_w<<<dim3(4 * bper), dim3(256), 0, stream>>>(ca);
    }

    // QKV projections: A = fp32 inputs via async gload + fragment-time cvt
    {
        GArgs ga;
        ga.A[0] = q_in; ga.A[1] = k_in; ga.A[2] = v_in;
        ga.Bm[0] = wqb; ga.Bm[1] = wkb; ga.Bm[2] = wvb;
        ga.bias[0] = bq; ga.bias[1] = bk; ga.bias[2] = bv;
        ga.C[0] = Qb; ga.C[1] = Kb; ga.C[2] = Vb;
        gemm_nt<0, 1><<<dim3(EMBED / 128, MROWS / 128, 3), dim3(256), 0, stream>>>(
            ga, MROWS, EMBED, EMBED);
    }

    sumv_kernel<<<dim3(NBH), dim3(256), 0, stream>>>(Vb, sumV);

    attn_mfma<<<dim3(SEQ / QT, NBH), dim3(256), 0, stream>>>(
        Qb, Kb, Vb, kpm, sumV, attn_out, ctx);

    // output projection -> fp32 out (bf16 A path)
    {
        GArgs ga;
        ga.A[0] = ctx;  ga.A[1] = ctx;  ga.A[2] = ctx;
        ga.Bm[0] = wob; ga.Bm[1] = wob; ga.Bm[2] = wob;
        ga.bias[0] = bo; ga.bias[1] = bo; ga.bias[2] = bo;
        ga.C[0] = out0; ga.C[1] = out0; ga.C[2] = out0;
        gemm_nt<1, 0><<<dim3(EMBED / 128, MROWS / 128, 1), dim3(256), 0, stream>>>(
            ga, MROWS, EMBED, EMBED);
    }
}